// Round 3
// baseline (123.366 us; speedup 1.0000x reference)
//
#include <hip/hip_runtime.h>
#include <math.h>

#define B_ROWS 4096
#define T_COLS 4096
#define NTHREADS 256
#define CHUNK 16                 // elements per thread = one 64B cache line
#define NWAVES (NTHREADS / 64)   // 4

__global__ __launch_bounds__(NTHREADS) void garch_fused(
    const float* __restrict__ x,
    const float* __restrict__ p_omega_log,
    const float* __restrict__ p_alpha_log,
    const float* __restrict__ p_beta_log,
    float* __restrict__ out)
{
    __shared__ float wA[NWAVES], wB[NWAVES], rSum[NWAVES], rSsq[NWAVES];

    const int t    = threadIdx.x;
    const int lane = t & 63;
    const int wv   = t >> 6;
    const long rbase = (long)blockIdx.x * T_COLS;

    // Uniform scalar parameter work
    float ea = expf(p_alpha_log[0]);
    float eb = expf(p_beta_log[0]);
    float denom = 1.0f + ea + eb;
    float omega = expf(p_omega_log[0]);
    float alpha = ea / denom;
    float beta  = eb / denom;
    float b2 = beta * beta, b4 = b2 * b2, b8 = b4 * b4, b16 = b8 * b8;

    // ---- Load: 4x float4 = this thread's own 64B line (wave: 4KB contiguous) ----
    const float4* xv = reinterpret_cast<const float4*>(x + rbase + (long)CHUNK * t);
    float4 v0 = xv[0], v1 = xv[1], v2 = xv[2], v3 = xv[3];
    float xr[CHUNK] = { v0.x, v0.y, v0.z, v0.w,  v1.x, v1.y, v1.z, v1.w,
                        v2.x, v2.y, v2.z, v2.w,  v3.x, v3.y, v3.z, v3.w };

    // prev = x[16t-1]: last element of neighbor thread's chunk
    float prev = __shfl_up(xr[CHUNK - 1], 1);
    if (lane == 0) prev = (t > 0) ? x[rbase + (long)CHUNK * t - 1] : 0.0f;

    // ---- Per-thread partials: sum/ssq + zero-init affine partial (A,B) ----
    float sum = 0.0f, ssq = 0.0f;
#pragma unroll
    for (int i = 0; i < CHUNK; ++i) { sum += xr[i]; ssq = fmaf(xr[i], xr[i], ssq); }

    // Thread 0: 15 steps (inputs x0..x14), A = beta^15.
    // Thread t>0: 16 steps (inputs prev, xr[0..14]), A = beta^16.
    float bpart = 0.0f;
    if (t > 0) bpart = fmaf(alpha, prev * prev, omega);
#pragma unroll
    for (int i = 0; i < CHUNK - 1; ++i)
        bpart = fmaf(beta, bpart, fmaf(alpha, xr[i] * xr[i], omega));
    float apart = (t == 0) ? (b8 * b4 * b2 * beta) : b16;

    // ---- Wave-level reduction (sum, ssq) ----
    float s1 = sum, s2 = ssq;
#pragma unroll
    for (int d = 32; d > 0; d >>= 1) {
        s1 += __shfl_xor(s1, d);
        s2 += __shfl_xor(s2, d);
    }

    // ---- Wave-level inclusive affine scan ----
    float ia = apart, ib = bpart;
#pragma unroll
    for (int d = 1; d < 64; d <<= 1) {
        float pa = __shfl_up(ia, d);
        float pb = __shfl_up(ib, d);
        if (lane >= d) { ib = fmaf(ia, pb, ib); ia = ia * pa; }
    }

    // ---- Single cross-wave handoff barrier ----
    if (lane == 0)  { rSum[wv] = s1; rSsq[wv] = s2; }
    if (lane == 63) { wA[wv] = ia;   wB[wv] = ib;  }
    __syncthreads();

    float tsum = rSum[0] + rSum[1] + rSum[2] + rSum[3];
    float tssq = rSsq[0] + rSsq[1] + rSsq[2] + rSsq[3];
    float s0 = (tssq - tsum * tsum * (1.0f / T_COLS)) * (1.0f / (T_COLS - 1));
    s0 = fmaxf(s0, 0.0f);

    // Apply preceding waves' aggregate maps to s0
    float sw = s0;
#pragma unroll
    for (int w = 0; w < NWAVES - 1; ++w)
        if (w < wv) sw = fmaf(wA[w], sw, wB[w]);

    // Exclusive intra-wave prefix -> entry state sigma2_{16t-1} (s0 for t==0)
    float ea_ = __shfl_up(ia, 1);
    float eb_ = __shfl_up(ib, 1);
    if (lane == 0) { ea_ = 1.0f; eb_ = 0.0f; }
    float s = fmaf(ea_, sw, eb_);

    // ---- Replay chunk from entry state, sqrt into registers ----
    float o[CHUNK];
    if (t == 0) {
        o[0] = __builtin_amdgcn_sqrtf(s);                     // t=0 output is sqrt(s0)
#pragma unroll
        for (int i = 0; i < CHUNK - 1; ++i) {
            s = fmaf(beta, s, fmaf(alpha, xr[i] * xr[i], omega));
            o[1 + i] = __builtin_amdgcn_sqrtf(s);
        }
    } else {
        s = fmaf(beta, s, fmaf(alpha, prev * prev, omega));
        o[0] = __builtin_amdgcn_sqrtf(s);
#pragma unroll
        for (int i = 0; i < CHUNK - 1; ++i) {
            s = fmaf(beta, s, fmaf(alpha, xr[i] * xr[i], omega));
            o[1 + i] = __builtin_amdgcn_sqrtf(s);
        }
    }

    // ---- Store: 4x float4 into this thread's own 64B line ----
    float4* ov = reinterpret_cast<float4*>(out + rbase + (long)CHUNK * t);
    ov[0] = make_float4(o[0],  o[1],  o[2],  o[3]);
    ov[1] = make_float4(o[4],  o[5],  o[6],  o[7]);
    ov[2] = make_float4(o[8],  o[9],  o[10], o[11]);
    ov[3] = make_float4(o[12], o[13], o[14], o[15]);
}

extern "C" void kernel_launch(void* const* d_in, const int* in_sizes, int n_in,
                              void* d_out, int out_size, void* d_ws, size_t ws_size,
                              hipStream_t stream) {
    const float* x         = (const float*)d_in[0];
    const float* omega_log = (const float*)d_in[1];
    const float* alpha_log = (const float*)d_in[2];
    const float* beta_log  = (const float*)d_in[3];
    float* out = (float*)d_out;

    garch_fused<<<B_ROWS, NTHREADS, 0, stream>>>(x, omega_log, alpha_log, beta_log, out);
}

// Round 4
// 123.083 us; speedup vs baseline: 1.0023x; 1.0023x over previous
//
#include <hip/hip_runtime.h>
#include <math.h>

#define B_ROWS 4096
#define T_COLS 4096
#define NTHREADS 256
#define CHUNK 16                 // elements per thread = one 64B cache line
#define NWAVES (NTHREADS / 64)   // 4

// Force a (wave-uniform) float into an SGPR.
__device__ __forceinline__ float rfl(float v) {
    return __int_as_float(__builtin_amdgcn_readfirstlane(__float_as_int(v)));
}

__global__ __launch_bounds__(NTHREADS) void garch_fused(
    const float* __restrict__ x,
    const float* __restrict__ p_omega_log,
    const float* __restrict__ p_alpha_log,
    const float* __restrict__ p_beta_log,
    float* __restrict__ out)
{
    __shared__ float wA[NWAVES], wB[NWAVES], rSum[NWAVES], rSsq[NWAVES];

    const int t    = threadIdx.x;
    const int lane = t & 63;
    const int wv   = t >> 6;
    const long rbase = (long)blockIdx.x * T_COLS;

    // Uniform scalar parameter work -> SGPRs
    float ea_p = expf(p_alpha_log[0]);
    float eb_p = expf(p_beta_log[0]);
    float denom = 1.0f + ea_p + eb_p;
    float omega = rfl(expf(p_omega_log[0]));
    float alpha = rfl(ea_p / denom);
    float beta  = rfl(eb_p / denom);

    // beta powers 0..16 (uniform -> scalar regs; indexed only by constants)
    float bpow[CHUNK + 1];
    bpow[0] = 1.0f;
#pragma unroll
    for (int j = 1; j <= CHUNK; ++j) bpow[j] = bpow[j - 1] * beta;

    // ---- Load: 4x float4 = this thread's own 64B line ----
    const float4* xv = reinterpret_cast<const float4*>(x + rbase + (long)CHUNK * t);
    float4 v0 = xv[0], v1 = xv[1], v2 = xv[2], v3 = xv[3];
    float xr[CHUNK] = { v0.x, v0.y, v0.z, v0.w,  v1.x, v1.y, v1.z, v1.w,
                        v2.x, v2.y, v2.z, v2.w,  v3.x, v3.y, v3.z, v3.w };

    // prev = x[16t-1]: last element of neighbor thread's chunk
    float prev = __shfl_up(xr[CHUNK - 1], 1);
    if (lane == 0) prev = (t > 0) ? x[rbase + (long)CHUNK * t - 1] : 0.0f;

    // ---- Per-thread sum/ssq ----
    float sum = 0.0f, ssq = 0.0f;
#pragma unroll
    for (int i = 0; i < CHUNK; ++i) { sum += xr[i]; ssq = fmaf(xr[i], xr[i], ssq); }

    // ---- Zero-init recurrence partials, SAVING intermediates Z[] ----
    // t>0 : steps j=0..15 with inputs (prev, xr[0..14]); Z[j] = chain value Z_j.
    // t==0: steps j=0..14 with inputs xr[0..14];        Z[j+1] = chain value Z_j (Z[0] unused).
    float Z[CHUNK];
    float z;
    if (t > 0) { z = fmaf(alpha, prev * prev, omega); Z[0] = z; }
    else       { z = 0.0f;                            Z[0] = 0.0f; }
#pragma unroll
    for (int i = 0; i < CHUNK - 1; ++i) {
        z = fmaf(beta, z, fmaf(alpha, xr[i] * xr[i], omega));
        Z[i + 1] = z;
    }
    float bpart = z;
    float apart = (t == 0) ? bpow[15] : bpow[16];

    // ---- Wave-level reduction (sum, ssq) ----
    float s1 = sum, s2 = ssq;
#pragma unroll
    for (int d = 32; d > 0; d >>= 1) {
        s1 += __shfl_xor(s1, d);
        s2 += __shfl_xor(s2, d);
    }

    // ---- Wave-level inclusive affine scan over (apart, bpart) ----
    float ia = apart, ib = bpart;
#pragma unroll
    for (int d = 1; d < 64; d <<= 1) {
        float pa = __shfl_up(ia, d);
        float pb = __shfl_up(ib, d);
        if (lane >= d) { ib = fmaf(ia, pb, ib); ia = ia * pa; }
    }

    // ---- Single cross-wave handoff barrier ----
    if (lane == 0)  { rSum[wv] = s1; rSsq[wv] = s2; }
    if (lane == 63) { wA[wv] = ia;   wB[wv] = ib;  }
    __syncthreads();

    float tsum = rSum[0] + rSum[1] + rSum[2] + rSum[3];
    float tssq = rSsq[0] + rSsq[1] + rSsq[2] + rSsq[3];
    float s0 = (tssq - tsum * tsum * (1.0f / T_COLS)) * (1.0f / (T_COLS - 1));
    s0 = fmaxf(s0, 0.0f);

    // Apply preceding waves' aggregate maps to s0
    float sw = s0;
#pragma unroll
    for (int w = 0; w < NWAVES - 1; ++w)
        if (w < wv) sw = fmaf(wA[w], sw, wB[w]);

    // Exclusive intra-wave prefix -> entry state s = sigma2_{16t-1} (s0 for t==0)
    float pea = __shfl_up(ia, 1);
    float peb = __shfl_up(ib, 1);
    if (lane == 0) { pea = 1.0f; peb = 0.0f; }
    float s = fmaf(pea, sw, peb);

    // ---- Outputs: independent o_j = sqrt(beta^{...} * s + Z[j]), store immediately ----
    float4* ov = reinterpret_cast<float4*>(out + rbase + (long)CHUNK * t);
    if (t == 0) {
        float4 o;
        o.x = __builtin_amdgcn_sqrtf(s);   // t=0 output is sqrt(s0)
        o.y = __builtin_amdgcn_sqrtf(fmaf(bpow[1], s, Z[1]));
        o.z = __builtin_amdgcn_sqrtf(fmaf(bpow[2], s, Z[2]));
        o.w = __builtin_amdgcn_sqrtf(fmaf(bpow[3], s, Z[3]));
        ov[0] = o;
#pragma unroll
        for (int k = 1; k < 4; ++k) {
            float4 q;
            q.x = __builtin_amdgcn_sqrtf(fmaf(bpow[4 * k + 0], s, Z[4 * k + 0]));
            q.y = __builtin_amdgcn_sqrtf(fmaf(bpow[4 * k + 1], s, Z[4 * k + 1]));
            q.z = __builtin_amdgcn_sqrtf(fmaf(bpow[4 * k + 2], s, Z[4 * k + 2]));
            q.w = __builtin_amdgcn_sqrtf(fmaf(bpow[4 * k + 3], s, Z[4 * k + 3]));
            ov[k] = q;
        }
    } else {
#pragma unroll
        for (int k = 0; k < 4; ++k) {
            float4 q;
            q.x = __builtin_amdgcn_sqrtf(fmaf(bpow[4 * k + 1], s, Z[4 * k + 0]));
            q.y = __builtin_amdgcn_sqrtf(fmaf(bpow[4 * k + 2], s, Z[4 * k + 1]));
            q.z = __builtin_amdgcn_sqrtf(fmaf(bpow[4 * k + 3], s, Z[4 * k + 2]));
            q.w = __builtin_amdgcn_sqrtf(fmaf(bpow[4 * k + 4], s, Z[4 * k + 3]));
            ov[k] = q;
        }
    }
}

extern "C" void kernel_launch(void* const* d_in, const int* in_sizes, int n_in,
                              void* d_out, int out_size, void* d_ws, size_t ws_size,
                              hipStream_t stream) {
    const float* x         = (const float*)d_in[0];
    const float* omega_log = (const float*)d_in[1];
    const float* alpha_log = (const float*)d_in[2];
    const float* beta_log  = (const float*)d_in[3];
    float* out = (float*)d_out;

    garch_fused<<<B_ROWS, NTHREADS, 0, stream>>>(x, omega_log, alpha_log, beta_log, out);
}